// Round 15
// baseline (206.658 us; speedup 1.0000x reference)
//
#include <hip/hip_runtime.h>
#include <cstddef>
#include <cstdint>

#define NUSERS 50000
#define NITEMS 50000
#define NNODES 100000
#define DIM    128
#define NLAYERS 3
#define NEDGES 600000
#define NPAD 100096           // 391*256

#define EBLK  8192            // edges per binning block
#define NBLK  74              // ceil(600000/8192)
#define NBUCK 782             // ceil(100000/128), bucket = dst>>7

// merged prologue block ranges
#define PRO_CONCAT 6250       // concat_dots blocks
#define PRO_WG     48         // wg_conv blocks (3*4096/256)
#define PRO_TOTAL  (PRO_CONCAT + PRO_WG + NBLK)

typedef __attribute__((ext_vector_type(8))) short short8;
typedef __attribute__((ext_vector_type(4))) float f32x4;
typedef __attribute__((ext_vector_type(2))) float f32x2;

__device__ __forceinline__ float bf_lo(unsigned u) { return __uint_as_float(u << 16); }
__device__ __forceinline__ float bf_hi(unsigned u) { return __uint_as_float(u & 0xffff0000u); }
__device__ __forceinline__ unsigned short f2bf(float f) {      // round-nearest-even
    unsigned b = __float_as_uint(f);
    return (unsigned short)((b + 0x7fffu + ((b >> 16) & 1u)) >> 16);
}
__device__ __forceinline__ unsigned pack2(float lo, float hi) {
    return ((unsigned)f2bf(hi) << 16) | (unsigned)f2bf(lo);
}

// async global->LDS 16B per lane; dst must be wave-uniform base (HW adds lane*16)
__device__ __forceinline__ void async16(const void* g, void* l) {
    __builtin_amdgcn_global_load_lds(
        (const __attribute__((address_space(1))) unsigned int*)(uintptr_t)g,
        (__attribute__((address_space(3))) unsigned int*)(unsigned int)(uintptr_t)l,
        16, 0, 0);
}

// ---------------------------------------------------------------------------
// merged prologue: [0,6250) concat+layer0 dots (+fp8 shadow) | Wg conv |
//                  edge bucket histogram (block-major counts)
// ---------------------------------------------------------------------------
__global__ __launch_bounds__(256) void prologue_kernel(
        const float* __restrict__ ue, const float* __restrict__ ie,
        const float* __restrict__ Wa, const float* __restrict__ ba,
        const float* __restrict__ Wg, const int* __restrict__ dst,
        unsigned short* __restrict__ xb, unsigned char* __restrict__ xf8,
        float* __restrict__ a_src, float* __restrict__ a_dst,
        unsigned short* __restrict__ Bf, unsigned* __restrict__ counts) {
    __shared__ unsigned hist[NBUCK];
    const int blk = blockIdx.x;

    if (blk < PRO_CONCAT) {
        const int n = blk * 16 + (threadIdx.x >> 4);
        if (n >= NNODES) return;
        const int sub = threadIdx.x & 15;
        const float* r = (n < NUSERS) ? (ue + (size_t)n * DIM)
                                      : (ie + (size_t)(n - NUSERS) * DIM);
        const float4 v0 = *(const float4*)(r + sub * 8);
        const float4 v1 = *(const float4*)(r + sub * 8 + 4);
        const float4 wl0 = *(const float4*)(Wa + sub * 8);
        const float4 wl1 = *(const float4*)(Wa + sub * 8 + 4);
        const float4 wh0 = *(const float4*)(Wa + DIM + sub * 8);
        const float4 wh1 = *(const float4*)(Wa + DIM + sub * 8 + 4);

        uint4 o;
        o.x = pack2(v0.x, v0.y);
        o.y = pack2(v0.z, v0.w);
        o.z = pack2(v1.x, v1.y);
        o.w = pack2(v1.z, v1.w);
        *(uint4*)(xb + (size_t)n * DIM + sub * 8) = o;

        // fp8 shadow row (gather table)
        unsigned w0 = (unsigned)__builtin_amdgcn_cvt_pk_fp8_f32(v0.x, v0.y, 0, false);
        w0 = (unsigned)__builtin_amdgcn_cvt_pk_fp8_f32(v0.z, v0.w, (int)w0, true);
        unsigned w1 = (unsigned)__builtin_amdgcn_cvt_pk_fp8_f32(v1.x, v1.y, 0, false);
        w1 = (unsigned)__builtin_amdgcn_cvt_pk_fp8_f32(v1.z, v1.w, (int)w1, true);
        *(uint2*)(xf8 + (size_t)n * DIM + sub * 8) = make_uint2(w0, w1);

        float ps = v0.x * wl0.x + v0.y * wl0.y + v0.z * wl0.z + v0.w * wl0.w
                 + v1.x * wl1.x + v1.y * wl1.y + v1.z * wl1.z + v1.w * wl1.w;
        float pd = v0.x * wh0.x + v0.y * wh0.y + v0.z * wh0.z + v0.w * wh0.w
                 + v1.x * wh1.x + v1.y * wh1.y + v1.z * wh1.z + v1.w * wh1.w;
        #pragma unroll
        for (int off = 1; off < 16; off <<= 1) {
            ps += __shfl_xor(ps, off);
            pd += __shfl_xor(pd, off);
        }
        if (sub == 0) { a_src[n] = ps; a_dst[n] = pd + ba[0]; }
    } else if (blk < PRO_CONCAT + PRO_WG) {
        const int tid = (blk - PRO_CONCAT) * 256 + threadIdx.x;
        if (tid >= NLAYERS * 4096) return;
        const int l    = tid >> 12;
        const int slot = tid & 4095;
        const int lane = slot & 63;
        const int t2   = slot >> 6;
        const int nf   = t2 & 3;
        const int t3   = t2 >> 2;
        const int ks   = t3 & 7;
        const int nb   = t3 >> 3;
        const int col  = nb * 64 + nf * 16 + (lane & 15);
        const int k0   = ks * 32 + (lane >> 4) * 8;
        const float* wsrc = Wg + (size_t)l * 256 * DIM;
        unsigned short o[8];
        #pragma unroll
        for (int j = 0; j < 8; ++j) o[j] = f2bf(wsrc[(size_t)(k0 + j) * DIM + col]);
        *(short8*)(Bf + (size_t)tid * 8) = *(short8*)o;
    } else {
        const int bblk = blk - PRO_CONCAT - PRO_WG;
        for (int i = threadIdx.x; i < NBUCK; i += 256) hist[i] = 0;
        __syncthreads();
        const int base = bblk * EBLK;
        const int end  = (base + EBLK < NEDGES) ? base + EBLK : NEDGES;
        for (int e = base + threadIdx.x; e < end; e += 256)
            atomicAdd(&hist[dst[e] >> 7], 1u);
        __syncthreads();
        for (int i = threadIdx.x; i < NBUCK; i += 256)
            counts[(size_t)bblk * NBUCK + i] = hist[i];
    }
}

// ---------------------------------------------------------------------------
// wave-per-bucket exclusive scan over the 74 per-block counts (parallel)
// ---------------------------------------------------------------------------
__global__ __launch_bounds__(256) void scan_blocks_kernel(
        unsigned* __restrict__ counts, unsigned* __restrict__ totals) {
    const int b = blockIdx.x * 4 + (threadIdx.x >> 6);
    if (b >= NBUCK) return;
    const int l = threadIdx.x & 63;

    const unsigned c0 = counts[(size_t)l * NBUCK + b];            // blocks 0..63
    const unsigned c1 = (64 + l < NBLK)
                        ? counts[(size_t)(64 + l) * NBUCK + b] : 0;

    unsigned s0 = c0, s1 = c1;
    #pragma unroll
    for (int o = 1; o < 64; o <<= 1) {
        const unsigned t0 = (unsigned)__shfl_up((int)s0, o);
        const unsigned t1 = (unsigned)__shfl_up((int)s1, o);
        if (l >= o) { s0 += t0; s1 += t1; }
    }
    const unsigned tot0 = (unsigned)__shfl((int)s0, 63);
    const unsigned tot1 = (unsigned)__shfl((int)s1, NBLK - 65);   // lane 9

    counts[(size_t)l * NBUCK + b] = s0 - c0;
    if (64 + l < NBLK)
        counts[(size_t)(64 + l) * NBUCK + b] = tot0 + s1 - c1;
    if (l == 0) totals[b] = tot0 + tot1;
}

// exclusive scan of the 782 bucket totals -> bucketbase
__global__ __launch_bounds__(1024) void bucketbase_kernel(
        const unsigned* __restrict__ totals, unsigned* __restrict__ bucketbase) {
    const int b = threadIdx.x;
    const unsigned v = (b < NBUCK) ? totals[b] : 0u;
    const int lane = b & 63, w = b >> 6;
    unsigned s = v;
    #pragma unroll
    for (int o = 1; o < 64; o <<= 1) {
        const unsigned t = (unsigned)__shfl_up((int)s, o);
        if (lane >= o) s += t;
    }
    __shared__ unsigned wsum[16];
    if (lane == 63) wsum[w] = s;
    __syncthreads();
    unsigned add = 0;
    #pragma unroll
    for (int j = 0; j < 15; ++j) if (w > j) add += wsum[j];
    if (b < NBUCK) bucketbase[b] = s + add - v;
    if (b == NBUCK - 1) bucketbase[NBUCK] = s + add;   // == NEDGES
}

__global__ __launch_bounds__(256) void bin_scatter_kernel(
        const int* __restrict__ src, const int* __restrict__ dst,
        const unsigned* __restrict__ counts, const unsigned* __restrict__ bucketbase,
        unsigned* __restrict__ pairs) {
    __shared__ unsigned off[NBUCK];
    for (int i = threadIdx.x; i < NBUCK; i += 256)
        off[i] = bucketbase[i] + counts[(size_t)blockIdx.x * NBUCK + i];
    __syncthreads();
    const int base = blockIdx.x * EBLK;
    const int end  = (base + EBLK < NEDGES) ? base + EBLK : NEDGES;
    for (int e = base + threadIdx.x; e < end; e += 256) {
        const int d = dst[e];
        const unsigned pos = atomicAdd(&off[d >> 7], 1u);
        pairs[pos] = ((unsigned)(d & 127) << 17) | (unsigned)src[e];
    }
}

__global__ __launch_bounds__(256) void bucket_csr_kernel(
        const unsigned* __restrict__ pairs, const unsigned* __restrict__ bucketbase,
        int* __restrict__ row_start, int* __restrict__ csr_src) {
    __shared__ unsigned deg[128], fill[128], wtot[2];
    const int b = blockIdx.x;
    const unsigned seg0 = bucketbase[b], seg1 = bucketbase[b + 1];
    const int t = threadIdx.x;
    if (t < 128) deg[t] = 0;
    __syncthreads();
    for (unsigned i = seg0 + t; i < seg1; i += 256)
        atomicAdd(&deg[pairs[i] >> 17], 1u);
    __syncthreads();
    unsigned incl = 0, v = 0;
    if (t < 128) {
        v = deg[t];
        unsigned s = v;
        #pragma unroll
        for (int o = 1; o < 64; o <<= 1) {
            const unsigned tmp = (unsigned)__shfl_up((int)s, o);
            if ((t & 63) >= o) s += tmp;
        }
        if ((t & 63) == 63) wtot[t >> 6] = s;
        incl = s;
    }
    __syncthreads();
    if (t < 128) {
        if (t >= 64) incl += wtot[0];
        const unsigned excl = incl - v;
        fill[t] = excl;
        const int node = b * 128 + t;
        if (node < NNODES) row_start[node] = (int)(seg0 + excl);
    }
    __syncthreads();
    for (unsigned i = seg0 + t; i < seg1; i += 256) {
        const unsigned p = pairs[i];
        const unsigned r = atomicAdd(&fill[p >> 17], 1u);
        csr_src[seg0 + r] = (int)(p & 0x1ffffu);
    }
    if (b == 0 && t == 0) row_start[NNODES] = NEDGES;
}

// ---------------------------------------------------------------------------
// FUSED layer: gather-agg (fp8 rows, half the fabric miss traffic) into LDS
// + bf16 MFMA GEMM + ReLU + next-layer dots. 32-row tile, 17KB LDS.
// ---------------------------------------------------------------------------
__global__ __launch_bounds__(256, 6) void fused_layer_kernel(
        const unsigned short* __restrict__ xin,
        const unsigned char* __restrict__ xf8in,
        const int* __restrict__ row_start, const int* __restrict__ csr_src,
        const float* __restrict__ a_src, const float* __restrict__ a_dst,
        const unsigned short* __restrict__ bfr, const float* __restrict__ bg,
        const float* __restrict__ wa_next, const float* __restrict__ ba_next,
        float* __restrict__ a_src_next, float* __restrict__ a_dst_next,
        float* __restrict__ xout_f32, unsigned short* __restrict__ xout_bf,
        unsigned char* __restrict__ xf8out,
        int write_f32, int do_dots) {
    __shared__ unsigned short At[2][32 * 128];      // 16 KB
    __shared__ float psS[4][32], psD[4][32];        // 1 KB

    const int tid  = threadIdx.x;
    const int lane = tid & 63;
    const int wid  = tid >> 6;
    const int mbase = blockIdx.x * 32;

    // ---- phase 1: async-DMA xin rows -> At[0] (pre-swizzled source) ----
    #pragma unroll
    for (int i = 0; i < 2; ++i) {
        const int lrow = i * 16 + wid * 4 + (lane >> 4);           // 0..31
        const int c    = (lane & 15) ^ (lrow & 7);
        async16(xin + (size_t)(mbase + lrow) * DIM + c * 8,
                &At[0][(i * 16 + wid * 4) * 128]);                 // uniform base
    }

    // ---- phase 2: gather agg (fp8 rows) for this block's 32 rows -> At[1] ----
    {
        const int q   = tid >> 4;          // quarter 0..15
        const int sub = lane & 15;
        const int qb  = lane & 48;
        #pragma unroll
        for (int it = 0; it < 2; ++it) {
            const int n = mbase + it * 16 + q;                     // < 100000
            const int beg = row_start[n], end = row_start[n + 1];
            const float adst = a_dst[n];
            float a0 = 0, a1 = 0, a2 = 0, a3 = 0, a4 = 0, a5 = 0, a6 = 0, a7 = 0;
            for (int base = beg; base < end; base += 16) {
                const int rem = end - base;
                const int cnt = rem < 16 ? rem : 16;
                int   idx_l = 0;
                float att_l = 0.0f;
                if (sub < cnt) {
                    idx_l = csr_src[base + sub];
                    att_l = 1.0f / (1.0f + __expf(-(a_src[idx_l] + adst)));
                }
                int i = 0;
                for (; i + 3 < cnt; i += 4) {
                    const int   s0 = __shfl(idx_l, qb + i);
                    const int   s1 = __shfl(idx_l, qb + i + 1);
                    const int   s2 = __shfl(idx_l, qb + i + 2);
                    const int   s3 = __shfl(idx_l, qb + i + 3);
                    const float w0 = __shfl(att_l, qb + i);
                    const float w1 = __shfl(att_l, qb + i + 1);
                    const float w2 = __shfl(att_l, qb + i + 2);
                    const float w3 = __shfl(att_l, qb + i + 3);
                    const uint2 u0 = *(const uint2*)(xf8in + (size_t)s0 * DIM + sub * 8);
                    const uint2 u1 = *(const uint2*)(xf8in + (size_t)s1 * DIM + sub * 8);
                    const uint2 u2 = *(const uint2*)(xf8in + (size_t)s2 * DIM + sub * 8);
                    const uint2 u3 = *(const uint2*)(xf8in + (size_t)s3 * DIM + sub * 8);
                    {
                        const f32x2 p0 = __builtin_amdgcn_cvt_pk_f32_fp8((int)u0.x, false);
                        const f32x2 p1 = __builtin_amdgcn_cvt_pk_f32_fp8((int)u0.x, true);
                        const f32x2 p2 = __builtin_amdgcn_cvt_pk_f32_fp8((int)u0.y, false);
                        const f32x2 p3 = __builtin_amdgcn_cvt_pk_f32_fp8((int)u0.y, true);
                        a0 += p0[0] * w0;  a1 += p0[1] * w0;
                        a2 += p1[0] * w0;  a3 += p1[1] * w0;
                        a4 += p2[0] * w0;  a5 += p2[1] * w0;
                        a6 += p3[0] * w0;  a7 += p3[1] * w0;
                    }
                    {
                        const f32x2 p0 = __builtin_amdgcn_cvt_pk_f32_fp8((int)u1.x, false);
                        const f32x2 p1 = __builtin_amdgcn_cvt_pk_f32_fp8((int)u1.x, true);
                        const f32x2 p2 = __builtin_amdgcn_cvt_pk_f32_fp8((int)u1.y, false);
                        const f32x2 p3 = __builtin_amdgcn_cvt_pk_f32_fp8((int)u1.y, true);
                        a0 += p0[0] * w1;  a1 += p0[1] * w1;
                        a2 += p1[0] * w1;  a3 += p1[1] * w1;
                        a4 += p2[0] * w1;  a5 += p2[1] * w1;
                        a6 += p3[0] * w1;  a7 += p3[1] * w1;
                    }
                    {
                        const f32x2 p0 = __builtin_amdgcn_cvt_pk_f32_fp8((int)u2.x, false);
                        const f32x2 p1 = __builtin_amdgcn_cvt_pk_f32_fp8((int)u2.x, true);
                        const f32x2 p2 = __builtin_amdgcn_cvt_pk_f32_fp8((int)u2.y, false);
                        const f32x2 p3 = __builtin_amdgcn_cvt_pk_f32_fp8((int)u2.y, true);
                        a0 += p0[0] * w2;  a1 += p0[1] * w2;
                        a2 += p1[0] * w2;  a3 += p1[1] * w2;
                        a4 += p2[0] * w2;  a5 += p2[1] * w2;
                        a6 += p3[0] * w2;  a7 += p3[1] * w2;
                    }
                    {
                        const f32x2 p0 = __builtin_amdgcn_cvt_pk_f32_fp8((int)u3.x, false);
                        const f32x2 p1 = __builtin_amdgcn_cvt_pk_f32_fp8((int)u3.x, true);
                        const f32x2 p2 = __builtin_amdgcn_cvt_pk_f32_fp8((int)u3.y, false);
                        const f32x2 p3 = __builtin_amdgcn_cvt_pk_f32_fp8((int)u3.y, true);
                        a0 += p0[0] * w3;  a1 += p0[1] * w3;
                        a2 += p1[0] * w3;  a3 += p1[1] * w3;
                        a4 += p2[0] * w3;  a5 += p2[1] * w3;
                        a6 += p3[0] * w3;  a7 += p3[1] * w3;
                    }
                }
                for (; i < cnt; ++i) {
                    const int   s = __shfl(idx_l, qb + i);
                    const float w = __shfl(att_l, qb + i);
                    const uint2 u = *(const uint2*)(xf8in + (size_t)s * DIM + sub * 8);
                    const f32x2 p0 = __builtin_amdgcn_cvt_pk_f32_fp8((int)u.x, false);
                    const f32x2 p1 = __builtin_amdgcn_cvt_pk_f32_fp8((int)u.x, true);
                    const f32x2 p2 = __builtin_amdgcn_cvt_pk_f32_fp8((int)u.y, false);
                    const f32x2 p3 = __builtin_amdgcn_cvt_pk_f32_fp8((int)u.y, true);
                    a0 += p0[0] * w;  a1 += p0[1] * w;
                    a2 += p1[0] * w;  a3 += p1[1] * w;
                    a4 += p2[0] * w;  a5 += p2[1] * w;
                    a6 += p3[0] * w;  a7 += p3[1] * w;
                }
            }
            uint4 o;
            o.x = pack2(a0, a1);
            o.y = pack2(a2, a3);
            o.z = pack2(a4, a5);
            o.w = pack2(a6, a7);
            const int rl = it * 16 + q;                            // 0..31
            *(uint4*)&At[1][rl * 128 + ((sub ^ (rl & 7)) << 3)] = o;
        }
    }

    asm volatile("s_waitcnt vmcnt(0) lgkmcnt(0)" ::: "memory");
    __builtin_amdgcn_s_barrier();

    // ---- phase 3: MFMA; wave on disjoint 32x32 sub-tile ----
    const int l16 = lane & 15, kq = lane >> 4;
    const unsigned short* bfw = bfr + (size_t)(wid >> 1) * (8 * 4 * 64 * 8);
    const int nfo = (wid & 1) * 2;

    f32x4 acc[2][2] = {};

    #pragma unroll
    for (int ks = 0; ks < 8; ++ks) {
        const int h = ks >> 2, ksl = ks & 3;
        short8 b[2], a[2];
        #pragma unroll
        for (int nf = 0; nf < 2; ++nf)
            b[nf] = *(const short8*)(bfw + ((size_t)(ks * 4 + nfo + nf) * 64 + lane) * 8);
        #pragma unroll
        for (int mf = 0; mf < 2; ++mf) {
            const int row   = mf * 16 + l16;                       // 0..31
            const int chunk = (ksl * 4 + kq) ^ (row & 7);
            a[mf] = *(const short8*)&At[h][row * 128 + chunk * 8];
        }
        #pragma unroll
        for (int mf = 0; mf < 2; ++mf)
            #pragma unroll
            for (int nf = 0; nf < 2; ++nf)
                acc[mf][nf] = __builtin_amdgcn_mfma_f32_16x16x32_bf16(
                    a[mf], b[nf], acc[mf][nf], 0, 0, 0);
    }

    // ---- phase 4: epilogue (bias+relu store + fp8 shadow + fused dots) ----
    const int rsub = kq * 4;
    float waS[2] = {0, 0}, waD[2] = {0, 0}, bias[2];
    #pragma unroll
    for (int nf = 0; nf < 2; ++nf) {
        const int col = wid * 32 + nf * 16 + l16;
        bias[nf] = bg[col];
        if (do_dots) { waS[nf] = wa_next[col]; waD[nf] = wa_next[DIM + col]; }
    }
    #pragma unroll
    for (int mf = 0; mf < 2; ++mf) {
        #pragma unroll
        for (int j = 0; j < 4; ++j) {
            const int row = mbase + mf * 16 + rsub + j;
            float s = 0.0f, d = 0.0f;
            #pragma unroll
            for (int nf = 0; nf < 2; ++nf) {
                const int col = wid * 32 + nf * 16 + l16;
                const float v = fmaxf(acc[mf][nf][j] + bias[nf], 0.0f);
                if (write_f32) {
                    xout_f32[(size_t)row * DIM + col] = v;
                } else {
                    const unsigned short bv = f2bf(v);
                    const unsigned pb = (unsigned)(unsigned short)__shfl_xor((int)bv, 1);
                    const float vn = __shfl_xor(v, 1);
                    if (!(l16 & 1)) {
                        *(unsigned*)(xout_bf + (size_t)row * DIM + col) =
                            (unsigned)bv | (pb << 16);
                        const unsigned pk = (unsigned)
                            __builtin_amdgcn_cvt_pk_fp8_f32(v, vn, 0, false);
                        *(unsigned short*)(xf8out + (size_t)row * DIM + col) =
                            (unsigned short)(pk & 0xffffu);
                    }
                }
                s += v * waS[nf];
                d += v * waD[nf];
            }
            if (do_dots) {
                #pragma unroll
                for (int off = 1; off < 16; off <<= 1) {
                    s += __shfl_xor(s, off);
                    d += __shfl_xor(d, off);
                }
                if (l16 == 0) {
                    const int rl = mf * 16 + rsub + j;
                    psS[wid][rl] = s;
                    psD[wid][rl] = d;
                }
            }
        }
    }
    if (do_dots) {
        __syncthreads();
        if (tid < 32) {
            const int row = mbase + tid;
            a_src_next[row] = psS[0][tid] + psS[1][tid] + psS[2][tid] + psS[3][tid];
            a_dst_next[row] = psD[0][tid] + psD[1][tid] + psD[2][tid] + psD[3][tid]
                            + ba_next[0];
        }
    }
}

// ---------------------------------------------------------------------------
extern "C" void kernel_launch(void* const* d_in, const int* in_sizes, int n_in,
                              void* d_out, int out_size, void* d_ws, size_t ws_size,
                              hipStream_t stream) {
    const int*   edge = (const int*)d_in[0];       // [2, E]
    const float* ue   = (const float*)d_in[1];
    const float* ie   = (const float*)d_in[2];
    const float* Wa   = (const float*)d_in[3];     // [3, 256, 1]
    const float* ba   = (const float*)d_in[4];     // [3, 1]
    const float* Wg   = (const float*)d_in[5];     // [3, 256, 128]
    const float* bg   = (const float*)d_in[6];     // [3, 128]

    const int* src = edge;
    const int* dst = edge + NEDGES;

    float* x = (float*)d_out;                      // final f32 output

    // ---- workspace layout ----
    unsigned short* xb0  = (unsigned short*)d_ws;            // NPAD*128 bf16
    unsigned short* xb1  = xb0 + (size_t)NPAD * DIM;         // NPAD*128 bf16
    unsigned short* bfr  = xb1 + (size_t)NPAD * DIM;         // 3*32768 bf16
    float* aSA        = (float*)(bfr + NLAYERS * 32768);     // NPAD f
    float* aDA        = aSA + NPAD;                          // NPAD f
    float* aSB        = aDA + NPAD;                          // NPAD f
    float* aDB        = aSB + NPAD;                          // NPAD f
    int*   row_start  = (int*)(aDB + NPAD);                  // NPAD+256 i
    int*   csr_src    = row_start + NPAD + 256;              // NEDGES i
    unsigned* pairs   = (unsigned*)(csr_src + NEDGES);       // NEDGES u
    unsigned* counts  = pairs + NEDGES;                      // NBLK*NBUCK u
    unsigned* totals  = counts + (size_t)NBLK * NBUCK;       // NBUCK u
    unsigned* bbase   = totals + NBUCK;                      // NBUCK+1 u
    unsigned char* xf8_0 = (unsigned char*)(bbase + NBUCK + 8);  // NPAD*128 B
    unsigned char* xf8_1 = xf8_0 + (size_t)NPAD * DIM;           // NPAD*128 B

    // merged prologue: concat+dots+fp8 | Wg conv | bucket histogram
    prologue_kernel<<<PRO_TOTAL, 256, 0, stream>>>(
        ue, ie, Wa, ba, Wg, dst, xb0, xf8_0, aSA, aDA, bfr, counts);

    // ---- binned CSR build ----
    scan_blocks_kernel<<<(NBUCK + 3) / 4, 256, 0, stream>>>(counts, totals);
    bucketbase_kernel<<<1, 1024, 0, stream>>>(totals, bbase);
    bin_scatter_kernel<<<NBLK, 256, 0, stream>>>(src, dst, counts, bbase, pairs);
    bucket_csr_kernel<<<NBUCK, 256, 0, stream>>>(pairs, bbase, row_start, csr_src);

    const int blocks = NNODES / 32;                          // 3125 exact

    // layer 0: xb0/xf8_0 -> xb1/xf8_1, dots for layer 1 into B
    fused_layer_kernel<<<blocks, 256, 0, stream>>>(
        xb0, xf8_0, row_start, csr_src, aSA, aDA,
        bfr, bg, Wa + 256, ba + 1, aSB, aDB,
        x, xb1, xf8_1, 0, 1);
    // layer 1: xb1/xf8_1 -> xb0/xf8_0, dots for layer 2 into A
    fused_layer_kernel<<<blocks, 256, 0, stream>>>(
        xb1, xf8_1, row_start, csr_src, aSB, aDB,
        bfr + 32768, bg + DIM, Wa + 512, ba + 2, aSA, aDA,
        x, xb0, xf8_0, 0, 1);
    // layer 2: xb0/xf8_0 -> f32 output
    fused_layer_kernel<<<blocks, 256, 0, stream>>>(
        xb0, xf8_0, row_start, csr_src, aSA, aDA,
        bfr + 65536, bg + 2 * DIM, Wa, ba, aSB, aDB,
        x, xb1, xf8_1, 1, 0);
}

// Round 16
// 188.004 us; speedup vs baseline: 1.0992x; 1.0992x over previous
//
#include <hip/hip_runtime.h>
#include <cstddef>
#include <cstdint>

#define NUSERS 50000
#define NITEMS 50000
#define NNODES 100000
#define DIM    128
#define NLAYERS 3
#define NEDGES 600000
#define NPAD 100096           // 391*256

#define EBLK  8192            // edges per binning block
#define NBLK  74              // ceil(600000/8192)
#define NBUCK 782             // ceil(100000/128), bucket = dst>>7

// merged prologue block ranges
#define PRO_CONCAT 6250       // concat_dots blocks
#define PRO_WG     48         // wg_conv blocks (3*4096/256)
#define PRO_TOTAL  (PRO_CONCAT + PRO_WG + NBLK)

typedef __attribute__((ext_vector_type(8))) short short8;
typedef __attribute__((ext_vector_type(4))) float f32x4;

__device__ __forceinline__ float bf_lo(unsigned u) { return __uint_as_float(u << 16); }
__device__ __forceinline__ float bf_hi(unsigned u) { return __uint_as_float(u & 0xffff0000u); }
__device__ __forceinline__ unsigned short f2bf(float f) {      // round-nearest-even
    unsigned b = __float_as_uint(f);
    return (unsigned short)((b + 0x7fffu + ((b >> 16) & 1u)) >> 16);
}
__device__ __forceinline__ unsigned pack2(float lo, float hi) {
    return ((unsigned)f2bf(hi) << 16) | (unsigned)f2bf(lo);
}

// async global->LDS 16B per lane; dst must be wave-uniform base (HW adds lane*16)
__device__ __forceinline__ void async16(const void* g, void* l) {
    __builtin_amdgcn_global_load_lds(
        (const __attribute__((address_space(1))) unsigned int*)(uintptr_t)g,
        (__attribute__((address_space(3))) unsigned int*)(unsigned int)(uintptr_t)l,
        16, 0, 0);
}

// ---------------------------------------------------------------------------
// merged prologue: [0,6250) concat+layer0 dots | [6250,6298) Wg conv |
//                  [6298,6372) edge bucket histogram (block-major counts)
// ---------------------------------------------------------------------------
__global__ __launch_bounds__(256) void prologue_kernel(
        const float* __restrict__ ue, const float* __restrict__ ie,
        const float* __restrict__ Wa, const float* __restrict__ ba,
        const float* __restrict__ Wg, const int* __restrict__ dst,
        unsigned short* __restrict__ xb,
        float* __restrict__ a_src, float* __restrict__ a_dst,
        unsigned short* __restrict__ Bf, unsigned* __restrict__ counts) {
    __shared__ unsigned hist[NBUCK];
    const int blk = blockIdx.x;

    if (blk < PRO_CONCAT) {
        const int n = blk * 16 + (threadIdx.x >> 4);
        if (n >= NNODES) return;
        const int sub = threadIdx.x & 15;
        const float* r = (n < NUSERS) ? (ue + (size_t)n * DIM)
                                      : (ie + (size_t)(n - NUSERS) * DIM);
        const float4 v0 = *(const float4*)(r + sub * 8);
        const float4 v1 = *(const float4*)(r + sub * 8 + 4);
        const float4 wl0 = *(const float4*)(Wa + sub * 8);
        const float4 wl1 = *(const float4*)(Wa + sub * 8 + 4);
        const float4 wh0 = *(const float4*)(Wa + DIM + sub * 8);
        const float4 wh1 = *(const float4*)(Wa + DIM + sub * 8 + 4);

        uint4 o;
        o.x = pack2(v0.x, v0.y);
        o.y = pack2(v0.z, v0.w);
        o.z = pack2(v1.x, v1.y);
        o.w = pack2(v1.z, v1.w);
        *(uint4*)(xb + (size_t)n * DIM + sub * 8) = o;

        float ps = v0.x * wl0.x + v0.y * wl0.y + v0.z * wl0.z + v0.w * wl0.w
                 + v1.x * wl1.x + v1.y * wl1.y + v1.z * wl1.z + v1.w * wl1.w;
        float pd = v0.x * wh0.x + v0.y * wh0.y + v0.z * wh0.z + v0.w * wh0.w
                 + v1.x * wh1.x + v1.y * wh1.y + v1.z * wh1.z + v1.w * wh1.w;
        #pragma unroll
        for (int off = 1; off < 16; off <<= 1) {
            ps += __shfl_xor(ps, off);
            pd += __shfl_xor(pd, off);
        }
        if (sub == 0) { a_src[n] = ps; a_dst[n] = pd + ba[0]; }
    } else if (blk < PRO_CONCAT + PRO_WG) {
        const int tid = (blk - PRO_CONCAT) * 256 + threadIdx.x;
        if (tid >= NLAYERS * 4096) return;
        const int l    = tid >> 12;
        const int slot = tid & 4095;
        const int lane = slot & 63;
        const int t2   = slot >> 6;
        const int nf   = t2 & 3;
        const int t3   = t2 >> 2;
        const int ks   = t3 & 7;
        const int nb   = t3 >> 3;
        const int col  = nb * 64 + nf * 16 + (lane & 15);
        const int k0   = ks * 32 + (lane >> 4) * 8;
        const float* wsrc = Wg + (size_t)l * 256 * DIM;
        unsigned short o[8];
        #pragma unroll
        for (int j = 0; j < 8; ++j) o[j] = f2bf(wsrc[(size_t)(k0 + j) * DIM + col]);
        *(short8*)(Bf + (size_t)tid * 8) = *(short8*)o;
    } else {
        const int bblk = blk - PRO_CONCAT - PRO_WG;
        for (int i = threadIdx.x; i < NBUCK; i += 256) hist[i] = 0;
        __syncthreads();
        const int base = bblk * EBLK;
        const int end  = (base + EBLK < NEDGES) ? base + EBLK : NEDGES;
        for (int e = base + threadIdx.x; e < end; e += 256)
            atomicAdd(&hist[dst[e] >> 7], 1u);
        __syncthreads();
        for (int i = threadIdx.x; i < NBUCK; i += 256)
            counts[(size_t)bblk * NBUCK + i] = hist[i];
    }
}

// ---------------------------------------------------------------------------
// wave-per-bucket exclusive scan over the 74 per-block counts (parallel)
// ---------------------------------------------------------------------------
__global__ __launch_bounds__(256) void scan_blocks_kernel(
        unsigned* __restrict__ counts, unsigned* __restrict__ totals) {
    const int b = blockIdx.x * 4 + (threadIdx.x >> 6);
    if (b >= NBUCK) return;
    const int l = threadIdx.x & 63;

    const unsigned c0 = counts[(size_t)l * NBUCK + b];            // blocks 0..63
    const unsigned c1 = (64 + l < NBLK)
                        ? counts[(size_t)(64 + l) * NBUCK + b] : 0;

    unsigned s0 = c0, s1 = c1;
    #pragma unroll
    for (int o = 1; o < 64; o <<= 1) {
        const unsigned t0 = (unsigned)__shfl_up((int)s0, o);
        const unsigned t1 = (unsigned)__shfl_up((int)s1, o);
        if (l >= o) { s0 += t0; s1 += t1; }
    }
    const unsigned tot0 = (unsigned)__shfl((int)s0, 63);
    const unsigned tot1 = (unsigned)__shfl((int)s1, NBLK - 65);   // lane 9

    counts[(size_t)l * NBUCK + b] = s0 - c0;
    if (64 + l < NBLK)
        counts[(size_t)(64 + l) * NBUCK + b] = tot0 + s1 - c1;
    if (l == 0) totals[b] = tot0 + tot1;
}

// exclusive scan of the 782 bucket totals -> bucketbase
__global__ __launch_bounds__(1024) void bucketbase_kernel(
        const unsigned* __restrict__ totals, unsigned* __restrict__ bucketbase) {
    const int b = threadIdx.x;
    const unsigned v = (b < NBUCK) ? totals[b] : 0u;
    const int lane = b & 63, w = b >> 6;
    unsigned s = v;
    #pragma unroll
    for (int o = 1; o < 64; o <<= 1) {
        const unsigned t = (unsigned)__shfl_up((int)s, o);
        if (lane >= o) s += t;
    }
    __shared__ unsigned wsum[16];
    if (lane == 63) wsum[w] = s;
    __syncthreads();
    unsigned add = 0;
    #pragma unroll
    for (int j = 0; j < 15; ++j) if (w > j) add += wsum[j];
    if (b < NBUCK) bucketbase[b] = s + add - v;
    if (b == NBUCK - 1) bucketbase[NBUCK] = s + add;   // == NEDGES
}

__global__ __launch_bounds__(256) void bin_scatter_kernel(
        const int* __restrict__ src, const int* __restrict__ dst,
        const unsigned* __restrict__ counts, const unsigned* __restrict__ bucketbase,
        unsigned* __restrict__ pairs) {
    __shared__ unsigned off[NBUCK];
    for (int i = threadIdx.x; i < NBUCK; i += 256)
        off[i] = bucketbase[i] + counts[(size_t)blockIdx.x * NBUCK + i];
    __syncthreads();
    const int base = blockIdx.x * EBLK;
    const int end  = (base + EBLK < NEDGES) ? base + EBLK : NEDGES;
    for (int e = base + threadIdx.x; e < end; e += 256) {
        const int d = dst[e];
        const unsigned pos = atomicAdd(&off[d >> 7], 1u);
        pairs[pos] = ((unsigned)(d & 127) << 17) | (unsigned)src[e];
    }
}

__global__ __launch_bounds__(256) void bucket_csr_kernel(
        const unsigned* __restrict__ pairs, const unsigned* __restrict__ bucketbase,
        int* __restrict__ row_start, int* __restrict__ csr_src) {
    __shared__ unsigned deg[128], fill[128], wtot[2];
    const int b = blockIdx.x;
    const unsigned seg0 = bucketbase[b], seg1 = bucketbase[b + 1];
    const int t = threadIdx.x;
    if (t < 128) deg[t] = 0;
    __syncthreads();
    for (unsigned i = seg0 + t; i < seg1; i += 256)
        atomicAdd(&deg[pairs[i] >> 17], 1u);
    __syncthreads();
    unsigned incl = 0, v = 0;
    if (t < 128) {
        v = deg[t];
        unsigned s = v;
        #pragma unroll
        for (int o = 1; o < 64; o <<= 1) {
            const unsigned tmp = (unsigned)__shfl_up((int)s, o);
            if ((t & 63) >= o) s += tmp;
        }
        if ((t & 63) == 63) wtot[t >> 6] = s;
        incl = s;
    }
    __syncthreads();
    if (t < 128) {
        if (t >= 64) incl += wtot[0];
        const unsigned excl = incl - v;
        fill[t] = excl;
        const int node = b * 128 + t;
        if (node < NNODES) row_start[node] = (int)(seg0 + excl);
    }
    __syncthreads();
    for (unsigned i = seg0 + t; i < seg1; i += 256) {
        const unsigned p = pairs[i];
        const unsigned r = atomicAdd(&fill[p >> 17], 1u);
        csr_src[seg0 + r] = (int)(p & 0x1ffffu);
    }
    if (b == 0 && t == 0) row_start[NNODES] = NEDGES;
}

// ---------------------------------------------------------------------------
// FUSED layer: gather-agg into LDS + MFMA GEMM + ReLU + next-layer dots.
// 32-row tile, 17KB LDS -> ~8 blocks/CU (gather TLP preserved).
// agg never touches HBM. Ping-pong x / a buffers.
// ---------------------------------------------------------------------------
__global__ __launch_bounds__(256, 6) void fused_layer_kernel(
        const unsigned short* __restrict__ xin,
        const int* __restrict__ row_start, const int* __restrict__ csr_src,
        const float* __restrict__ a_src, const float* __restrict__ a_dst,
        const unsigned short* __restrict__ bfr, const float* __restrict__ bg,
        const float* __restrict__ wa_next, const float* __restrict__ ba_next,
        float* __restrict__ a_src_next, float* __restrict__ a_dst_next,
        float* __restrict__ xout_f32, unsigned short* __restrict__ xout_bf,
        int write_f32, int do_dots) {
    __shared__ unsigned short At[2][32 * 128];      // 16 KB
    __shared__ float psS[4][32], psD[4][32];        // 1 KB

    const int tid  = threadIdx.x;
    const int lane = tid & 63;
    const int wid  = tid >> 6;
    const int mbase = blockIdx.x * 32;

    // ---- phase 1: async-DMA xin rows -> At[0] (pre-swizzled source) ----
    #pragma unroll
    for (int i = 0; i < 2; ++i) {
        const int lrow = i * 16 + wid * 4 + (lane >> 4);           // 0..31
        const int c    = (lane & 15) ^ (lrow & 7);
        async16(xin + (size_t)(mbase + lrow) * DIM + c * 8,
                &At[0][(i * 16 + wid * 4) * 128]);                 // uniform base
    }

    // ---- phase 2: gather agg for this block's 32 rows -> At[1] ----
    {
        const int q   = tid >> 4;          // quarter 0..15
        const int sub = lane & 15;
        const int qb  = lane & 48;
        #pragma unroll
        for (int it = 0; it < 2; ++it) {
            const int n = mbase + it * 16 + q;                     // < 100000
            const int beg = row_start[n], end = row_start[n + 1];
            const float adst = a_dst[n];
            float a0 = 0, a1 = 0, a2 = 0, a3 = 0, a4 = 0, a5 = 0, a6 = 0, a7 = 0;
            for (int base = beg; base < end; base += 16) {
                const int rem = end - base;
                const int cnt = rem < 16 ? rem : 16;
                int   idx_l = 0;
                float att_l = 0.0f;
                if (sub < cnt) {
                    idx_l = csr_src[base + sub];
                    att_l = 1.0f / (1.0f + __expf(-(a_src[idx_l] + adst)));
                }
                int i = 0;
                for (; i + 3 < cnt; i += 4) {
                    const int   s0 = __shfl(idx_l, qb + i);
                    const int   s1 = __shfl(idx_l, qb + i + 1);
                    const int   s2 = __shfl(idx_l, qb + i + 2);
                    const int   s3 = __shfl(idx_l, qb + i + 3);
                    const float w0 = __shfl(att_l, qb + i);
                    const float w1 = __shfl(att_l, qb + i + 1);
                    const float w2 = __shfl(att_l, qb + i + 2);
                    const float w3 = __shfl(att_l, qb + i + 3);
                    const uint4 u0 = *(const uint4*)(xin + (size_t)s0 * DIM + sub * 8);
                    const uint4 u1 = *(const uint4*)(xin + (size_t)s1 * DIM + sub * 8);
                    const uint4 u2 = *(const uint4*)(xin + (size_t)s2 * DIM + sub * 8);
                    const uint4 u3 = *(const uint4*)(xin + (size_t)s3 * DIM + sub * 8);
                    a0 += bf_lo(u0.x) * w0 + bf_lo(u1.x) * w1 + bf_lo(u2.x) * w2 + bf_lo(u3.x) * w3;
                    a1 += bf_hi(u0.x) * w0 + bf_hi(u1.x) * w1 + bf_hi(u2.x) * w2 + bf_hi(u3.x) * w3;
                    a2 += bf_lo(u0.y) * w0 + bf_lo(u1.y) * w1 + bf_lo(u2.y) * w2 + bf_lo(u3.y) * w3;
                    a3 += bf_hi(u0.y) * w0 + bf_hi(u1.y) * w1 + bf_hi(u2.y) * w2 + bf_hi(u3.y) * w3;
                    a4 += bf_lo(u0.z) * w0 + bf_lo(u1.z) * w1 + bf_lo(u2.z) * w2 + bf_lo(u3.z) * w3;
                    a5 += bf_hi(u0.z) * w0 + bf_hi(u1.z) * w1 + bf_hi(u2.z) * w2 + bf_hi(u3.z) * w3;
                    a6 += bf_lo(u0.w) * w0 + bf_lo(u1.w) * w1 + bf_lo(u2.w) * w2 + bf_lo(u3.w) * w3;
                    a7 += bf_hi(u0.w) * w0 + bf_hi(u1.w) * w1 + bf_hi(u2.w) * w2 + bf_hi(u3.w) * w3;
                }
                for (; i < cnt; ++i) {
                    const int   s = __shfl(idx_l, qb + i);
                    const float w = __shfl(att_l, qb + i);
                    const uint4 u = *(const uint4*)(xin + (size_t)s * DIM + sub * 8);
                    a0 += bf_lo(u.x) * w;  a1 += bf_hi(u.x) * w;
                    a2 += bf_lo(u.y) * w;  a3 += bf_hi(u.y) * w;
                    a4 += bf_lo(u.z) * w;  a5 += bf_hi(u.z) * w;
                    a6 += bf_lo(u.w) * w;  a7 += bf_hi(u.w) * w;
                }
            }
            uint4 o;
            o.x = pack2(a0, a1);
            o.y = pack2(a2, a3);
            o.z = pack2(a4, a5);
            o.w = pack2(a6, a7);
            const int rl = it * 16 + q;                            // 0..31
            *(uint4*)&At[1][rl * 128 + ((sub ^ (rl & 7)) << 3)] = o;
        }
    }

    asm volatile("s_waitcnt vmcnt(0) lgkmcnt(0)" ::: "memory");
    __builtin_amdgcn_s_barrier();

    // ---- phase 3: MFMA; wave on disjoint 32x32 sub-tile ----
    const int l16 = lane & 15, kq = lane >> 4;
    const unsigned short* bfw = bfr + (size_t)(wid >> 1) * (8 * 4 * 64 * 8);
    const int nfo = (wid & 1) * 2;

    f32x4 acc[2][2] = {};

    #pragma unroll
    for (int ks = 0; ks < 8; ++ks) {
        const int h = ks >> 2, ksl = ks & 3;
        short8 b[2], a[2];
        #pragma unroll
        for (int nf = 0; nf < 2; ++nf)
            b[nf] = *(const short8*)(bfw + ((size_t)(ks * 4 + nfo + nf) * 64 + lane) * 8);
        #pragma unroll
        for (int mf = 0; mf < 2; ++mf) {
            const int row   = mf * 16 + l16;                       // 0..31
            const int chunk = (ksl * 4 + kq) ^ (row & 7);
            a[mf] = *(const short8*)&At[h][row * 128 + chunk * 8];
        }
        #pragma unroll
        for (int mf = 0; mf < 2; ++mf)
            #pragma unroll
            for (int nf = 0; nf < 2; ++nf)
                acc[mf][nf] = __builtin_amdgcn_mfma_f32_16x16x32_bf16(
                    a[mf], b[nf], acc[mf][nf], 0, 0, 0);
    }

    // ---- phase 4: epilogue (bias+relu store + fused next-layer dots) ----
    const int rsub = kq * 4;
    float waS[2] = {0, 0}, waD[2] = {0, 0}, bias[2];
    #pragma unroll
    for (int nf = 0; nf < 2; ++nf) {
        const int col = wid * 32 + nf * 16 + l16;
        bias[nf] = bg[col];
        if (do_dots) { waS[nf] = wa_next[col]; waD[nf] = wa_next[DIM + col]; }
    }
    #pragma unroll
    for (int mf = 0; mf < 2; ++mf) {
        #pragma unroll
        for (int j = 0; j < 4; ++j) {
            const int row = mbase + mf * 16 + rsub + j;
            float s = 0.0f, d = 0.0f;
            #pragma unroll
            for (int nf = 0; nf < 2; ++nf) {
                const int col = wid * 32 + nf * 16 + l16;
                const float v = fmaxf(acc[mf][nf][j] + bias[nf], 0.0f);
                if (write_f32) {
                    xout_f32[(size_t)row * DIM + col] = v;
                } else {
                    const unsigned short bv = f2bf(v);
                    const unsigned pb = (unsigned)(unsigned short)__shfl_xor((int)bv, 1);
                    if (!(l16 & 1))
                        *(unsigned*)(xout_bf + (size_t)row * DIM + col) =
                            (unsigned)bv | (pb << 16);
                }
                s += v * waS[nf];
                d += v * waD[nf];
            }
            if (do_dots) {
                #pragma unroll
                for (int off = 1; off < 16; off <<= 1) {
                    s += __shfl_xor(s, off);
                    d += __shfl_xor(d, off);
                }
                if (l16 == 0) {
                    const int rl = mf * 16 + rsub + j;
                    psS[wid][rl] = s;
                    psD[wid][rl] = d;
                }
            }
        }
    }
    if (do_dots) {
        __syncthreads();
        if (tid < 32) {
            const int row = mbase + tid;
            a_src_next[row] = psS[0][tid] + psS[1][tid] + psS[2][tid] + psS[3][tid];
            a_dst_next[row] = psD[0][tid] + psD[1][tid] + psD[2][tid] + psD[3][tid]
                            + ba_next[0];
        }
    }
}

// ---------------------------------------------------------------------------
extern "C" void kernel_launch(void* const* d_in, const int* in_sizes, int n_in,
                              void* d_out, int out_size, void* d_ws, size_t ws_size,
                              hipStream_t stream) {
    const int*   edge = (const int*)d_in[0];       // [2, E]
    const float* ue   = (const float*)d_in[1];
    const float* ie   = (const float*)d_in[2];
    const float* Wa   = (const float*)d_in[3];     // [3, 256, 1]
    const float* ba   = (const float*)d_in[4];     // [3, 1]
    const float* Wg   = (const float*)d_in[5];     // [3, 256, 128]
    const float* bg   = (const float*)d_in[6];     // [3, 128]

    const int* src = edge;
    const int* dst = edge + NEDGES;

    float* x = (float*)d_out;                      // final f32 output

    // ---- workspace layout ----
    unsigned short* xb0  = (unsigned short*)d_ws;            // NPAD*128 bf16
    unsigned short* xb1  = xb0 + (size_t)NPAD * DIM;         // NPAD*128 bf16
    unsigned short* bfr  = xb1 + (size_t)NPAD * DIM;         // 3*32768 bf16
    float* aSA        = (float*)(bfr + NLAYERS * 32768);     // NPAD f
    float* aDA        = aSA + NPAD;                          // NPAD f
    float* aSB        = aDA + NPAD;                          // NPAD f
    float* aDB        = aSB + NPAD;                          // NPAD f
    int*   row_start  = (int*)(aDB + NPAD);                  // NPAD+256 i
    int*   csr_src    = row_start + NPAD + 256;              // NEDGES i
    unsigned* pairs   = (unsigned*)(csr_src + NEDGES);       // NEDGES u
    unsigned* counts  = pairs + NEDGES;                      // NBLK*NBUCK u
    unsigned* totals  = counts + (size_t)NBLK * NBUCK;       // NBUCK u
    unsigned* bbase   = totals + NBUCK;                      // NBUCK+1 u

    // merged prologue: concat+dots | Wg conv | bucket histogram
    prologue_kernel<<<PRO_TOTAL, 256, 0, stream>>>(
        ue, ie, Wa, ba, Wg, dst, xb0, aSA, aDA, bfr, counts);

    // ---- binned CSR build ----
    scan_blocks_kernel<<<(NBUCK + 3) / 4, 256, 0, stream>>>(counts, totals);
    bucketbase_kernel<<<1, 1024, 0, stream>>>(totals, bbase);
    bin_scatter_kernel<<<NBLK, 256, 0, stream>>>(src, dst, counts, bbase, pairs);
    bucket_csr_kernel<<<NBUCK, 256, 0, stream>>>(pairs, bbase, row_start, csr_src);

    const int blocks = NNODES / 32;                          // 3125 exact

    // layer 0: xb0 -> xb1, dots for layer 1 into B
    fused_layer_kernel<<<blocks, 256, 0, stream>>>(
        xb0, row_start, csr_src, aSA, aDA,
        bfr, bg, Wa + 256, ba + 1, aSB, aDB,
        x, xb1, 0, 1);
    // layer 1: xb1 -> xb0, dots for layer 2 into A
    fused_layer_kernel<<<blocks, 256, 0, stream>>>(
        xb1, row_start, csr_src, aSB, aDB,
        bfr + 32768, bg + DIM, Wa + 512, ba + 2, aSA, aDA,
        x, xb0, 0, 1);
    // layer 2: xb0 -> f32 output, no dots
    fused_layer_kernel<<<blocks, 256, 0, stream>>>(
        xb0, row_start, csr_src, aSA, aDA,
        bfr + 65536, bg + 2 * DIM, Wa, ba, aSB, aDB,
        x, xb1, 1, 0);
}